// Round 1
// baseline (1089.192 us; speedup 1.0000x reference)
//
#include <hip/hip_runtime.h>
#include <hip/hip_bf16.h>

// Problem constants
#define BB   8
#define NN   4096
#define DD   512
#define HH   8
#define DHH  64
#define WW   128
#define PP   32      // windows = NN / WW
#define DISP 64

// ---------------------------------------------------------------------------
// Kernel A: qkv = roll(x,-DISP) @ Wqkv  -> scatter into windowed q/k/v
//   q/k/v layout: [b][h][pi][w][dh], token n(shifted) = w*32 + pi
// Tiled fp32 GEMM: 128x128 tile, BK=16, 256 threads, 8x8 micro-tile.
// ---------------------------------------------------------------------------
__global__ __launch_bounds__(256) void qkv_gemm(const float* __restrict__ x,
                                                const float* __restrict__ Wqkv,
                                                float* __restrict__ qw,
                                                float* __restrict__ kw,
                                                float* __restrict__ vw) {
    __shared__ float As[16 * 132];  // A transposed: As[k][m], m stride 1
    __shared__ float Bs[16 * 132];  // B natural:    Bs[k][c]
    const int tid  = threadIdx.x;
    const int brow = blockIdx.x;    // 256 row-tiles
    const int bcol = blockIdx.y;    // 12 col-tiles
    const int ty = tid >> 4, tx = tid & 15;
    const int m0 = ty * 8, n0 = tx * 8;
    const int c0 = bcol * 128;

    float acc[8][8];
#pragma unroll
    for (int i = 0; i < 8; ++i)
#pragma unroll
        for (int j = 0; j < 8; ++j) acc[i][j] = 0.f;

    for (int k0 = 0; k0 < DD; k0 += 16) {
        // A tile: 128 rows x 16 k  (apply cyclic shift on the row read)
#pragma unroll
        for (int t = 0; t < 2; ++t) {
            int i = tid + t * 256;          // 512 float4s
            int row = i >> 2, k4 = (i & 3) << 2;
            int r = brow * 128 + row;
            int b = r >> 12, n = r & 4095;
            const float4 a = *(const float4*)(x + (size_t)((b << 12) | ((n + DISP) & 4095)) * DD + k0 + k4);
            As[(k4 + 0) * 132 + row] = a.x;
            As[(k4 + 1) * 132 + row] = a.y;
            As[(k4 + 2) * 132 + row] = a.z;
            As[(k4 + 3) * 132 + row] = a.w;
        }
        // B tile: 16 k x 128 cols
#pragma unroll
        for (int t = 0; t < 2; ++t) {
            int i = tid + t * 256;
            int k = i >> 5, c4 = (i & 31) << 2;
            *(float4*)&Bs[k * 132 + c4] = *(const float4*)(Wqkv + (size_t)(k0 + k) * 1536 + c0 + c4);
        }
        __syncthreads();
#pragma unroll
        for (int kk = 0; kk < 16; ++kk) {
            float a8[8], b8[8];
            *(float4*)&a8[0] = *(float4*)&As[kk * 132 + m0];
            *(float4*)&a8[4] = *(float4*)&As[kk * 132 + m0 + 4];
            *(float4*)&b8[0] = *(float4*)&Bs[kk * 132 + n0];
            *(float4*)&b8[4] = *(float4*)&Bs[kk * 132 + n0 + 4];
#pragma unroll
            for (int i = 0; i < 8; ++i)
#pragma unroll
                for (int j = 0; j < 8; ++j) acc[i][j] = fmaf(a8[i], b8[j], acc[i][j]);
        }
        __syncthreads();
    }

    // Epilogue: scatter to windowed layout. 8 cols (n0..n0+7) stay inside one
    // 64-wide head block, so which/h/dh0 are per-thread constants.
    const int cbase = c0 + n0;
    const int which = cbase >> 9;
    const int h     = (cbase >> 6) & 7;
    const int dh0   = cbase & 63;
    float* dst = (which == 0) ? qw : ((which == 1) ? kw : vw);
#pragma unroll
    for (int i = 0; i < 8; ++i) {
        int r = brow * 128 + m0 + i;
        int b = r >> 12, n = r & 4095;
        int w = n >> 5, pi = n & 31;   // n = w*32 + pi
        size_t base = ((((size_t)(b * 8 + h) * 32 + pi) * 128 + w) * 64 + dh0);
        *(float4*)(dst + base)     = make_float4(acc[i][0], acc[i][1], acc[i][2], acc[i][3]);
        *(float4*)(dst + base + 4) = make_float4(acc[i][4], acc[i][5], acc[i][6], acc[i][7]);
    }
}

// ---------------------------------------------------------------------------
// Kernel B: per-window attention. One block per (b,h,pi).
//   S = qk^T*scale + pos[j-i+127] + mask; softmax rows; O = S @ V
//   O row w written to ao[b][pi*128 + w][h*64 + dh]  (reference's out-rearrange)
// ---------------------------------------------------------------------------
__global__ __launch_bounds__(256) void win_attn(const float* __restrict__ qw,
                                                const float* __restrict__ kw,
                                                const float* __restrict__ vw,
                                                const float* __restrict__ pos,
                                                float* __restrict__ ao) {
    __shared__ float bufA[128 * 68];   // qsT[64][132] (8448), later vs[128][68] (8704)
    __shared__ float bufB[64 * 132];   // ksT[64][132]
    __shared__ float S[128 * 129];

    const int tid = threadIdx.x;
    const int blk = blockIdx.x;        // b*256 + h*32 + pi
    const int pi = blk & 31;
    const int h  = (blk >> 5) & 7;
    const int b  = blk >> 8;
    const size_t base = (((size_t)(b * 8 + h) * 32 + pi) * 128) * 64;
    const float* qg = qw + base;
    const float* kg = kw + base;
    const float* vg = vw + base;

    // load q,k transposed into LDS: buf[d][w], row stride 132
    for (int i = tid; i < 2048; i += 256) {
        int w = i >> 4, d4 = (i & 15) << 2;
        float4 qv = *(const float4*)(qg + w * 64 + d4);
        bufA[(d4 + 0) * 132 + w] = qv.x;
        bufA[(d4 + 1) * 132 + w] = qv.y;
        bufA[(d4 + 2) * 132 + w] = qv.z;
        bufA[(d4 + 3) * 132 + w] = qv.w;
        float4 kv = *(const float4*)(kg + w * 64 + d4);
        bufB[(d4 + 0) * 132 + w] = kv.x;
        bufB[(d4 + 1) * 132 + w] = kv.y;
        bufB[(d4 + 2) * 132 + w] = kv.z;
        bufB[(d4 + 3) * 132 + w] = kv.w;
    }
    __syncthreads();

    // S = q k^T  (8x8 micro-tile per thread)
    {
        const int ty = tid >> 4, tx = tid & 15;
        const int i0 = ty * 8, j0 = tx * 8;
        float acc[8][8];
#pragma unroll
        for (int i = 0; i < 8; ++i)
#pragma unroll
            for (int j = 0; j < 8; ++j) acc[i][j] = 0.f;
#pragma unroll 4
        for (int d = 0; d < 64; ++d) {
            float qv[8], kv[8];
            *(float4*)&qv[0] = *(float4*)&bufA[d * 132 + i0];
            *(float4*)&qv[4] = *(float4*)&bufA[d * 132 + i0 + 4];
            *(float4*)&kv[0] = *(float4*)&bufB[d * 132 + j0];
            *(float4*)&kv[4] = *(float4*)&bufB[d * 132 + j0 + 4];
#pragma unroll
            for (int i = 0; i < 8; ++i)
#pragma unroll
                for (int j = 0; j < 8; ++j) acc[i][j] = fmaf(qv[i], kv[j], acc[i][j]);
        }
#pragma unroll
        for (int ii = 0; ii < 8; ++ii)
#pragma unroll
            for (int jj = 0; jj < 8; ++jj) {
                int i = i0 + ii, j = j0 + jj;
                float s = acc[ii][jj] * 0.125f + pos[j - i + 127];
                if ((i >= 64) != (j >= 64)) s -= 1e9f;   // shift mask (additive)
                S[i * 129 + j] = s;
            }
    }
    __syncthreads();

    // load V into bufA (q no longer needed); overlaps with softmax below
    for (int i = tid; i < 2048; i += 256) {
        int k = i >> 4, d4 = (i & 15) << 2;
        *(float4*)&bufA[k * 68 + d4] = *(const float4*)(vg + k * 64 + d4);
    }

    // row softmax (threads 0..127, one row each)
    if (tid < 128) {
        float* Sr = &S[tid * 129];
        float m = -3.0e38f;
        for (int j = 0; j < 128; ++j) m = fmaxf(m, Sr[j]);
        float sum = 0.f;
        for (int j = 0; j < 128; ++j) { float e = __expf(Sr[j] - m); Sr[j] = e; sum += e; }
        float inv = 1.0f / sum;
        for (int j = 0; j < 128; ++j) Sr[j] *= inv;
    }
    __syncthreads();

    // O = P @ V   (thread: 4 rows x 8 cols)
    const int rg = tid >> 3, cg = tid & 7;
    const int r0 = rg * 4, c0 = cg * 8;
    float o[4][8];
#pragma unroll
    for (int i = 0; i < 4; ++i)
#pragma unroll
        for (int j = 0; j < 8; ++j) o[i][j] = 0.f;
#pragma unroll 4
    for (int k = 0; k < 128; ++k) {
        float p0 = S[(r0 + 0) * 129 + k];
        float p1 = S[(r0 + 1) * 129 + k];
        float p2 = S[(r0 + 2) * 129 + k];
        float p3 = S[(r0 + 3) * 129 + k];
        float v8[8];
        *(float4*)&v8[0] = *(float4*)&bufA[k * 68 + c0];
        *(float4*)&v8[4] = *(float4*)&bufA[k * 68 + c0 + 4];
#pragma unroll
        for (int j = 0; j < 8; ++j) {
            o[0][j] = fmaf(p0, v8[j], o[0][j]);
            o[1][j] = fmaf(p1, v8[j], o[1][j]);
            o[2][j] = fmaf(p2, v8[j], o[2][j]);
            o[3][j] = fmaf(p3, v8[j], o[3][j]);
        }
    }
#pragma unroll
    for (int rr = 0; rr < 4; ++rr) {
        size_t row = (size_t)b * 4096 + (size_t)pi * 128 + r0 + rr;   // n' = pi*128 + w
        float* dst = ao + row * 512 + h * 64 + c0;
        *(float4*)dst       = make_float4(o[rr][0], o[rr][1], o[rr][2], o[rr][3]);
        *(float4*)(dst + 4) = make_float4(o[rr][4], o[rr][5], o[rr][6], o[rr][7]);
    }
}

// ---------------------------------------------------------------------------
// Kernel C: out = roll(ao @ Wout + bout, +DISP)
// ---------------------------------------------------------------------------
__global__ __launch_bounds__(256) void out_proj(const float* __restrict__ ao,
                                                const float* __restrict__ Wout,
                                                const float* __restrict__ bout,
                                                float* __restrict__ out) {
    __shared__ float As[16 * 132];
    __shared__ float Bs[16 * 132];
    const int tid  = threadIdx.x;
    const int brow = blockIdx.x;    // 256
    const int bcol = blockIdx.y;    // 4
    const int ty = tid >> 4, tx = tid & 15;
    const int m0 = ty * 8, n0 = tx * 8;
    const int c0 = bcol * 128;

    float acc[8][8];
#pragma unroll
    for (int i = 0; i < 8; ++i)
#pragma unroll
        for (int j = 0; j < 8; ++j) acc[i][j] = 0.f;

    for (int k0 = 0; k0 < 512; k0 += 16) {
#pragma unroll
        for (int t = 0; t < 2; ++t) {
            int i = tid + t * 256;
            int row = i >> 2, k4 = (i & 3) << 2;
            int r = brow * 128 + row;
            const float4 a = *(const float4*)(ao + (size_t)r * 512 + k0 + k4);
            As[(k4 + 0) * 132 + row] = a.x;
            As[(k4 + 1) * 132 + row] = a.y;
            As[(k4 + 2) * 132 + row] = a.z;
            As[(k4 + 3) * 132 + row] = a.w;
        }
#pragma unroll
        for (int t = 0; t < 2; ++t) {
            int i = tid + t * 256;
            int k = i >> 5, c4 = (i & 31) << 2;
            *(float4*)&Bs[k * 132 + c4] = *(const float4*)(Wout + (size_t)(k0 + k) * 512 + c0 + c4);
        }
        __syncthreads();
#pragma unroll
        for (int kk = 0; kk < 16; ++kk) {
            float a8[8], b8[8];
            *(float4*)&a8[0] = *(float4*)&As[kk * 132 + m0];
            *(float4*)&a8[4] = *(float4*)&As[kk * 132 + m0 + 4];
            *(float4*)&b8[0] = *(float4*)&Bs[kk * 132 + n0];
            *(float4*)&b8[4] = *(float4*)&Bs[kk * 132 + n0 + 4];
#pragma unroll
            for (int i = 0; i < 8; ++i)
#pragma unroll
                for (int j = 0; j < 8; ++j) acc[i][j] = fmaf(a8[i], b8[j], acc[i][j]);
        }
        __syncthreads();
    }

    const int c = c0 + n0;
    const float4 bo0 = *(const float4*)(bout + c);
    const float4 bo1 = *(const float4*)(bout + c + 4);
#pragma unroll
    for (int i = 0; i < 8; ++i) {
        int r = brow * 128 + m0 + i;
        int b = r >> 12, n = r & 4095;
        int dstn = (n + DISP) & 4095;           // roll(+DISP)
        float* dst = out + (size_t)((b << 12) | dstn) * 512 + c;
        *(float4*)dst = make_float4(acc[i][0] + bo0.x, acc[i][1] + bo0.y,
                                    acc[i][2] + bo0.z, acc[i][3] + bo0.w);
        *(float4*)(dst + 4) = make_float4(acc[i][4] + bo1.x, acc[i][5] + bo1.y,
                                          acc[i][6] + bo1.z, acc[i][7] + bo1.w);
    }
}

// ---------------------------------------------------------------------------
extern "C" void kernel_launch(void* const* d_in, const int* in_sizes, int n_in,
                              void* d_out, int out_size, void* d_ws, size_t ws_size,
                              hipStream_t stream) {
    (void)in_sizes; (void)n_in; (void)out_size; (void)ws_size;
    const float* x    = (const float*)d_in[0];
    const float* Wqkv = (const float*)d_in[1];
    const float* pos  = (const float*)d_in[2];
    const float* Wout = (const float*)d_in[3];
    const float* bout = (const float*)d_in[4];
    float* out = (float*)d_out;

    const size_t T = (size_t)BB * HH * PP * WW * DHH;  // 16,777,216 per tensor
    float* qw = (float*)d_ws;
    float* kw = qw + T;
    float* vw = kw + T;
    float* ao = vw + T;   // [B][N][H*DH], token n' = pi*128 + w

    qkv_gemm<<<dim3(256, 12), 256, 0, stream>>>(x, Wqkv, qw, kw, vw);
    win_attn<<<dim3(2048), 256, 0, stream>>>(qw, kw, vw, pos, ao);
    out_proj<<<dim3(256, 4), 256, 0, stream>>>(ao, Wout, bout, out);
}

// Round 2
// 427.943 us; speedup vs baseline: 2.5452x; 2.5452x over previous
//
#include <hip/hip_runtime.h>
#include <hip/hip_bf16.h>

// Problem constants
#define BB   8
#define NN   4096
#define DD   512
#define HH   8
#define DHH  64
#define WW   128
#define PP   32      // windows = NN / WW
#define DISP 64

typedef __attribute__((ext_vector_type(8))) short bf16x8_t;       // 8 bf16 (4 VGPRs)
typedef __attribute__((ext_vector_type(4))) float f32x4_t;        // MFMA C/D
typedef __attribute__((ext_vector_type(8))) unsigned short u16x8; // raw bf16 bits

__device__ __forceinline__ unsigned short f2bf(float f) {
    unsigned int u = __float_as_uint(f);
    unsigned int r = (u + 0x7FFFu + ((u >> 16) & 1u)) >> 16;  // RNE
    return (unsigned short)r;
}
__device__ __forceinline__ float bf2f(unsigned short u) {
    return __uint_as_float(((unsigned int)u) << 16);
}

__device__ __forceinline__ void gload_lds16(const void* g, void* l) {
    __builtin_amdgcn_global_load_lds(
        (const __attribute__((address_space(1))) unsigned int*)g,
        (__attribute__((address_space(3))) unsigned int*)l, 16, 0, 0);
}

// ---------------------------------------------------------------------------
// Convert x (fp32) -> xb (bf16), applying cyclic shift roll(x,-DISP) so that
// xb rows are in SHIFTED token order (GEMM A reads become linear).
// ---------------------------------------------------------------------------
__global__ __launch_bounds__(256) void cvt_x_shift(const float* __restrict__ x,
                                                   unsigned short* __restrict__ xb) {
    int idx = blockIdx.x * 256 + threadIdx.x;     // 8192*256 threads, 8 elems each
    int e0 = idx * 8;
    int r = e0 >> 9, d = e0 & 511;
    int b = r >> 12, n = r & 4095;
    const float* src = x + (size_t)((b << 12) | ((n + DISP) & 4095)) * 512 + d;
    float4 f0 = *(const float4*)src;
    float4 f1 = *(const float4*)(src + 4);
    u16x8 p;
    p[0] = f2bf(f0.x); p[1] = f2bf(f0.y); p[2] = f2bf(f0.z); p[3] = f2bf(f0.w);
    p[4] = f2bf(f1.x); p[5] = f2bf(f1.y); p[6] = f2bf(f1.z); p[7] = f2bf(f1.w);
    *(u16x8*)(xb + (size_t)r * 512 + d) = p;
}

// ---------------------------------------------------------------------------
// Convert + transpose weights: WqkvT[n][k] (1536x512), WoutT[n][k] (512x512)
// ---------------------------------------------------------------------------
__global__ __launch_bounds__(256) void cvt_w(const float* __restrict__ Wqkv,
                                             const float* __restrict__ Wout,
                                             unsigned short* __restrict__ wqkvT,
                                             unsigned short* __restrict__ woutT) {
    int idx = blockIdx.x * 256 + threadIdx.x;    // 4096*256 = 1,048,576
    if (idx < 786432) {
        int n = idx >> 9, k = idx & 511;
        wqkvT[idx] = f2bf(Wqkv[(size_t)k * 1536 + n]);
    } else {
        int j = idx - 786432;
        int n = j >> 9, k = j & 511;
        woutT[j] = f2bf(Wout[(size_t)k * 512 + n]);
    }
}

// ---------------------------------------------------------------------------
// bf16 MFMA GEMM, m97 structure: 128x128 tile, BK=32, 4 waves, 16x16x32 MFMA.
//   A  [M][512] bf16 (row-major, K contiguous)
//   BT [N][512] bf16 (row-major, K contiguous)
// Epilogue QKV: split columns into q/k/v (c>>9), store bf16 to [32768][512].
// ---------------------------------------------------------------------------
__global__ __launch_bounds__(256) void gemm_qkv(const unsigned short* __restrict__ A,
                                                const unsigned short* __restrict__ BT,
                                                unsigned short* __restrict__ qw,
                                                unsigned short* __restrict__ kw,
                                                unsigned short* __restrict__ vw) {
    __shared__ unsigned short As[128 * 32];
    __shared__ unsigned short Bs[128 * 32];
    const int tid  = threadIdx.x;
    const int wv   = tid >> 6, lane = tid & 63;
    const int brow = blockIdx.x;            // 256
    const int bcol = blockIdx.y;            // 12
    const int wr = (wv >> 1) * 64, wc = (wv & 1) * 64;
    const int lr = lane >> 4, lc = lane & 15;
    const int kq = lr * 8;

    f32x4_t acc[4][4];
#pragma unroll
    for (int i = 0; i < 4; ++i)
#pragma unroll
        for (int j = 0; j < 4; ++j) acc[i][j] = (f32x4_t)0.f;

    const size_t arow0 = (size_t)brow * 128;
    const size_t brow0 = (size_t)bcol * 128;

    for (int k0 = 0; k0 < 512; k0 += 32) {
        // stage A,B: 8 chunks of 1KB each; wave wv owns chunks 2wv,2wv+1
#pragma unroll
        for (int i = 0; i < 2; ++i) {
            int chunk = wv * 2 + i;
            int idx = chunk * 64 + lane;        // 0..511
            int row = idx >> 2;                 // 0..127
            int koff = (idx & 3) * 8;
            gload_lds16(A  + (arow0 + row) * 512 + k0 + koff, &As[chunk * 512]);
            gload_lds16(BT + (brow0 + row) * 512 + k0 + koff, &Bs[chunk * 512]);
        }
        __syncthreads();
        bf16x8_t af[4], bfr[4];
#pragma unroll
        for (int mi = 0; mi < 4; ++mi)
            af[mi] = *(const bf16x8_t*)&As[(wr + mi * 16 + lc) * 32 + kq];
#pragma unroll
        for (int nj = 0; nj < 4; ++nj)
            bfr[nj] = *(const bf16x8_t*)&Bs[(wc + nj * 16 + lc) * 32 + kq];
#pragma unroll
        for (int mi = 0; mi < 4; ++mi)
#pragma unroll
            for (int nj = 0; nj < 4; ++nj)
                acc[mi][nj] = __builtin_amdgcn_mfma_f32_16x16x32_bf16(
                    af[mi], bfr[nj], acc[mi][nj], 0, 0, 0);
        __syncthreads();
    }

    // Epilogue: C row = (lane>>4)*4+reg, col = lane&15 within each 16x16 frag
#pragma unroll
    for (int nj = 0; nj < 4; ++nj) {
        int c = bcol * 128 + wc + nj * 16 + lc;
        int which = c >> 9, cc = c & 511;
        unsigned short* dst = (which == 0) ? qw : ((which == 1) ? kw : vw);
#pragma unroll
        for (int mi = 0; mi < 4; ++mi)
#pragma unroll
            for (int r = 0; r < 4; ++r) {
                int row = brow * 128 + wr + mi * 16 + lr * 4 + r;
                dst[(size_t)row * 512 + cc] = f2bf(acc[mi][nj][r]);
            }
    }
}

// ---------------------------------------------------------------------------
// out_proj GEMM: out = roll(ao @ Wout + bout, +DISP).  A = aob bf16 (token n'
// = pi*128+w order), BT = WoutT. fp32 output with bias + roll in epilogue.
// ---------------------------------------------------------------------------
__global__ __launch_bounds__(256) void gemm_out(const unsigned short* __restrict__ A,
                                                const unsigned short* __restrict__ BT,
                                                const float* __restrict__ bout,
                                                float* __restrict__ out) {
    __shared__ unsigned short As[128 * 32];
    __shared__ unsigned short Bs[128 * 32];
    const int tid  = threadIdx.x;
    const int wv   = tid >> 6, lane = tid & 63;
    const int brow = blockIdx.x;            // 256
    const int bcol = blockIdx.y;            // 4
    const int wr = (wv >> 1) * 64, wc = (wv & 1) * 64;
    const int lr = lane >> 4, lc = lane & 15;
    const int kq = lr * 8;

    f32x4_t acc[4][4];
#pragma unroll
    for (int i = 0; i < 4; ++i)
#pragma unroll
        for (int j = 0; j < 4; ++j) acc[i][j] = (f32x4_t)0.f;

    const size_t arow0 = (size_t)brow * 128;
    const size_t brow0 = (size_t)bcol * 128;

    for (int k0 = 0; k0 < 512; k0 += 32) {
#pragma unroll
        for (int i = 0; i < 2; ++i) {
            int chunk = wv * 2 + i;
            int idx = chunk * 64 + lane;
            int row = idx >> 2;
            int koff = (idx & 3) * 8;
            gload_lds16(A  + (arow0 + row) * 512 + k0 + koff, &As[chunk * 512]);
            gload_lds16(BT + (brow0 + row) * 512 + k0 + koff, &Bs[chunk * 512]);
        }
        __syncthreads();
        bf16x8_t af[4], bfr[4];
#pragma unroll
        for (int mi = 0; mi < 4; ++mi)
            af[mi] = *(const bf16x8_t*)&As[(wr + mi * 16 + lc) * 32 + kq];
#pragma unroll
        for (int nj = 0; nj < 4; ++nj)
            bfr[nj] = *(const bf16x8_t*)&Bs[(wc + nj * 16 + lc) * 32 + kq];
#pragma unroll
        for (int mi = 0; mi < 4; ++mi)
#pragma unroll
            for (int nj = 0; nj < 4; ++nj)
                acc[mi][nj] = __builtin_amdgcn_mfma_f32_16x16x32_bf16(
                    af[mi], bfr[nj], acc[mi][nj], 0, 0, 0);
        __syncthreads();
    }

#pragma unroll
    for (int nj = 0; nj < 4; ++nj) {
        int c = bcol * 128 + wc + nj * 16 + lc;
        float bias = bout[c];
#pragma unroll
        for (int mi = 0; mi < 4; ++mi)
#pragma unroll
            for (int r = 0; r < 4; ++r) {
                int row = brow * 128 + wr + mi * 16 + lr * 4 + r;
                int b = row >> 12, np = row & 4095;
                int dn = (np + DISP) & 4095;                 // roll(+DISP)
                out[(size_t)((b << 12) | dn) * 512 + c] = acc[mi][nj][r] + bias;
            }
    }
}

// ---------------------------------------------------------------------------
// Kernel B: per-window attention (fp32 math, bf16 in/out).
// One block per (b,h,pi). q/k/v natural layout [b*4096 + n][512] bf16,
// n = w*32 + pi (shifted order), col = h*64 + dh.
// ao written bf16 at token n' = pi*128 + w.
// ---------------------------------------------------------------------------
__global__ __launch_bounds__(256) void win_attn(const unsigned short* __restrict__ qw,
                                                const unsigned short* __restrict__ kw,
                                                const unsigned short* __restrict__ vw,
                                                const float* __restrict__ pos,
                                                unsigned short* __restrict__ aob) {
    __shared__ float bufA[128 * 68];   // qsT[64][132] (8448 fl), later vs[128][68]
    __shared__ float bufB[64 * 132];   // ksT[64][132]
    __shared__ float S[128 * 129];

    const int tid = threadIdx.x;
    const int blk = blockIdx.x;        // b*256 + h*32 + pi
    const int pi = blk & 31;
    const int h  = (blk >> 5) & 7;
    const int b  = blk >> 8;
    const size_t base = ((size_t)(b * 4096 + pi)) * 512 + h * 64;
    const unsigned short* qg = qw + base;
    const unsigned short* kg = kw + base;
    const unsigned short* vg = vw + base;   // token w at +w*16384

    // load q,k transposed into LDS: buf[d][w], row stride 132
    for (int i = tid; i < 1024; i += 256) {
        int w = i >> 3, d8 = (i & 7) << 3;
        u16x8 qv8 = *(const u16x8*)(qg + (size_t)w * 16384 + d8);
        u16x8 kv8 = *(const u16x8*)(kg + (size_t)w * 16384 + d8);
#pragma unroll
        for (int j = 0; j < 8; ++j) {
            bufA[(d8 + j) * 132 + w] = bf2f(qv8[j]);
            bufB[(d8 + j) * 132 + w] = bf2f(kv8[j]);
        }
    }
    __syncthreads();

    // S = q k^T  (8x8 micro-tile per thread)
    {
        const int ty = tid >> 4, tx = tid & 15;
        const int i0 = ty * 8, j0 = tx * 8;
        float acc[8][8];
#pragma unroll
        for (int i = 0; i < 8; ++i)
#pragma unroll
            for (int j = 0; j < 8; ++j) acc[i][j] = 0.f;
#pragma unroll 4
        for (int d = 0; d < 64; ++d) {
            float qv[8], kv[8];
            *(float4*)&qv[0] = *(float4*)&bufA[d * 132 + i0];
            *(float4*)&qv[4] = *(float4*)&bufA[d * 132 + i0 + 4];
            *(float4*)&kv[0] = *(float4*)&bufB[d * 132 + j0];
            *(float4*)&kv[4] = *(float4*)&bufB[d * 132 + j0 + 4];
#pragma unroll
            for (int i = 0; i < 8; ++i)
#pragma unroll
                for (int j = 0; j < 8; ++j) acc[i][j] = fmaf(qv[i], kv[j], acc[i][j]);
        }
#pragma unroll
        for (int ii = 0; ii < 8; ++ii)
#pragma unroll
            for (int jj = 0; jj < 8; ++jj) {
                int i = i0 + ii, j = j0 + jj;
                float s = acc[ii][jj] * 0.125f + pos[j - i + 127];
                if ((i >= 64) != (j >= 64)) s -= 1e9f;   // shift mask
                S[i * 129 + j] = s;
            }
    }
    __syncthreads();

    // load V into bufA (q no longer needed)
    for (int i = tid; i < 1024; i += 256) {
        int k = i >> 3, d8 = (i & 7) << 3;
        u16x8 vv8 = *(const u16x8*)(vg + (size_t)k * 16384 + d8);
#pragma unroll
        for (int j = 0; j < 8; ++j) bufA[k * 68 + d8 + j] = bf2f(vv8[j]);
    }

    // row softmax (threads 0..127, one row each)
    if (tid < 128) {
        float* Sr = &S[tid * 129];
        float m = -3.0e38f;
        for (int j = 0; j < 128; ++j) m = fmaxf(m, Sr[j]);
        float sum = 0.f;
        for (int j = 0; j < 128; ++j) { float e = __expf(Sr[j] - m); Sr[j] = e; sum += e; }
        float inv = 1.0f / sum;
        for (int j = 0; j < 128; ++j) Sr[j] *= inv;
    }
    __syncthreads();

    // O = P @ V   (thread: 4 rows x 8 cols)
    const int rg = tid >> 3, cg = tid & 7;
    const int r0 = rg * 4, c0 = cg * 8;
    float o[4][8];
#pragma unroll
    for (int i = 0; i < 4; ++i)
#pragma unroll
        for (int j = 0; j < 8; ++j) o[i][j] = 0.f;
#pragma unroll 4
    for (int k = 0; k < 128; ++k) {
        float p0 = S[(r0 + 0) * 129 + k];
        float p1 = S[(r0 + 1) * 129 + k];
        float p2 = S[(r0 + 2) * 129 + k];
        float p3 = S[(r0 + 3) * 129 + k];
        float v8[8];
        *(float4*)&v8[0] = *(float4*)&bufA[k * 68 + c0];
        *(float4*)&v8[4] = *(float4*)&bufA[k * 68 + c0 + 4];
#pragma unroll
        for (int j = 0; j < 8; ++j) {
            o[0][j] = fmaf(p0, v8[j], o[0][j]);
            o[1][j] = fmaf(p1, v8[j], o[1][j]);
            o[2][j] = fmaf(p2, v8[j], o[2][j]);
            o[3][j] = fmaf(p3, v8[j], o[3][j]);
        }
    }
#pragma unroll
    for (int rr = 0; rr < 4; ++rr) {
        size_t row = (size_t)b * 4096 + (size_t)pi * 128 + r0 + rr;   // n' = pi*128+w
        unsigned short* dst = aob + row * 512 + h * 64 + c0;
        u16x8 p;
#pragma unroll
        for (int j = 0; j < 8; ++j) p[j] = f2bf(o[rr][j]);
        *(u16x8*)dst = p;
    }
}

// ---------------------------------------------------------------------------
extern "C" void kernel_launch(void* const* d_in, const int* in_sizes, int n_in,
                              void* d_out, int out_size, void* d_ws, size_t ws_size,
                              hipStream_t stream) {
    (void)in_sizes; (void)n_in; (void)out_size; (void)ws_size;
    const float* x    = (const float*)d_in[0];
    const float* Wqkv = (const float*)d_in[1];
    const float* pos  = (const float*)d_in[2];
    const float* Wout = (const float*)d_in[3];
    const float* bout = (const float*)d_in[4];
    float* out = (float*)d_out;

    const size_t T = (size_t)BB * NN * 512;   // 16,777,216 elems
    unsigned short* xb    = (unsigned short*)d_ws;
    unsigned short* wqkvT = xb + T;           // 786,432
    unsigned short* woutT = wqkvT + 786432;   // 262,144
    unsigned short* qw    = woutT + 262144;
    unsigned short* kw    = qw + T;
    unsigned short* vw    = kw + T;
    unsigned short* aob   = vw + T;

    cvt_x_shift<<<dim3(8192), 256, 0, stream>>>(x, xb);
    cvt_w<<<dim3(4096), 256, 0, stream>>>(Wqkv, Wout, wqkvT, woutT);
    gemm_qkv<<<dim3(256, 12), 256, 0, stream>>>(xb, wqkvT, qw, kw, vw);
    win_attn<<<dim3(2048), 256, 0, stream>>>(qw, kw, vw, pos, aob);
    gemm_out<<<dim3(256, 4), 256, 0, stream>>>(aob, woutT, bout, out);
}